// Round 1
// baseline (128.674 us; speedup 1.0000x reference)
//
#include <hip/hip_runtime.h>

// StabilizedButterflyLayer: B=4096 rows, N=4096 cols, 12 butterfly stages.
// fp32 in / fp32 out. R5 restructure: stages 3-8 pair thread t with t^Delta
// (Delta=1..32) -- always inside one 64-lane wave -- so they are done as
// in-wave shuffle butterflies (DPP quad_perm for ^1/^2, ds_swizzle for
// ^4/^8/^16, shfl_xor for ^32) with NO barrier and NO LDS image. Only
// stages 9-11 (dist 512..2048, cross-wave) use an LDS exchange: natural
// write (2x ds_write_b128), ONE barrier, stride-512 conflict-free read,
// ping-ponged over 2 images. Barriers/block: 24 -> 8. LDS: 48KB -> 32KB.
//
// One-sided rotation: z' = c*z + sigma*s*p, sigma = +1 iff (t & Delta)
// (i.e. this thread holds the h=1 element of the pair). sigma is baked into
// the packed bf16 sin at preamble time -- bit-identical to the two-sided
// form, so absmax is unchanged vs the R4 kernel (0.03125 measured).
//
// Angle slot derivation for stage s (d = 2^s, elem e = 8t+j):
//   slot = ((e >> (s+1)) << s) | (e & (d-1))  -> 8 contiguous slots per
//   thread at base_s: s=3: 8*(t>>1); s=4: 16*(t>>2)+8*(t&1);
//   s=5: 32*(t>>3)+8*(t&3); s=6: 64*(t>>4)+8*(t&7);
//   s=7: 128*(t>>5)+8*(t&15); s=8: 256*(t>>6)+8*(t&31).
//   Partner t^Delta maps to the SAME base (flipped bit drops out) -- checked.
//
// 2-image / 1-barrier WAR safety: row r uses image r&1. Thread X's write of
// row r+2 (image p) is after barrier_{r+1}; every thread's read of row r
// (image p) precedes its own row-r+1 write, which precedes barrier_{r+1}.
//
// R4 lesson kept: __launch_bounds__(512, 2) -> 128-VGPR cap, 2 blocks/CU.
// Estimated live set: 72 packed angles + 8 z + 8 prefetch + ptrs ~= 115.
// R3 lesson: nontemporal builtins need clang ext_vector_type, not float4.
// R2 lesson: keep everything scalarized, no address-taken locals.

#define BLOCK 512
#define NROWS 8
#define NCOL  4096

typedef float floatx4 __attribute__((ext_vector_type(4)));

// theta -> packed {hi16: bf16(sgn*sin), lo16: bf16(cos-1)}; |theta| <~ 0.17
// so the 2-term polys are exact to ~1e-5. Rounding trick is pure mantissa
// round-to-nearest-even, sign rides along (bf16(-s) == -bf16(s)).
__device__ __forceinline__ unsigned int pack_cs(float th, float sgn) {
  float t2  = th * th;
  float s   = sgn * (th * fmaf(t2, fmaf(t2, 8.3333333e-3f, -1.6666667e-1f), 1.0f));
  float cm1 = t2 * fmaf(t2, 4.1666667e-2f, -0.5f);
  unsigned int uc = __float_as_uint(cm1);
  uc = (uc + 0x7fffu + ((uc >> 16) & 1u)) >> 16;
  unsigned int us = __float_as_uint(s);
  us = (us + 0x7fffu + ((us >> 16) & 1u)) & 0xffff0000u;
  return us | uc;
}

// Two-sided Givens on an owned pair: a' = c*a - s*b ; b' = s*a + c*b
#define ROT(a, b, cc) do {                                   \
    float cm1_ = __uint_as_float((cc) << 16);                \
    float s_   = __uint_as_float((cc) & 0xffff0000u);        \
    float y0_  = fmaf(cm1_, (a), fmaf(-s_, (b), (a)));       \
    float y1_  = fmaf(cm1_, (b), fmaf( s_, (a), (b)));       \
    (a) = y0_; (b) = y1_;                                    \
  } while (0)

// One-sided: z' = c*z + s_signed*p  (sigma pre-baked into packed sin)
#define ROT1(z, p, cc) do {                                  \
    float cm1_ = __uint_as_float((cc) << 16);                \
    float ss_  = __uint_as_float((cc) & 0xffff0000u);        \
    (z) = fmaf(cm1_, (z), fmaf(ss_, (p), (z)));              \
  } while (0)

// 3 in-thread stages (slot maps verified in R2; reused for groups A and D).
#define GROUP3(c0,c1,c2,c3,c4,c5,c6,c7,c8,c9,c10,c11) do {   \
    ROT(z0, z1, c0);  ROT(z2, z3, c1);                       \
    ROT(z4, z5, c2);  ROT(z6, z7, c3);                       \
    ROT(z0, z2, c4);  ROT(z1, z3, c5);                       \
    ROT(z4, z6, c6);  ROT(z5, z7, c7);                       \
    ROT(z0, z4, c8);  ROT(z1, z5, c9);                       \
    ROT(z2, z6, c10); ROT(z3, z7, c11);                      \
  } while (0)

// Cross-lane fetch of partner value, by thread-XOR distance.
// ^1/^2: DPP quad_perm (VALU pipe, full rate). quad_perm encodings:
//   xor1 = [1,0,3,2] = 0xB1 ; xor2 = [2,3,0,1] = 0x4E.
// ^4/^8/^16: ds_swizzle BitMode, offset = (xor<<10)|0x1F (and=0x1F, or=0).
// ^32: shfl_xor (ds_permute-based, full wave64).
#define SH_X1(v)  __int_as_float(__builtin_amdgcn_update_dpp(              \
    __float_as_int(v), __float_as_int(v), 0xB1, 0xF, 0xF, false))
#define SH_X2(v)  __int_as_float(__builtin_amdgcn_update_dpp(              \
    __float_as_int(v), __float_as_int(v), 0x4E, 0xF, 0xF, false))
#define SH_X4(v)  __int_as_float(__builtin_amdgcn_ds_swizzle(__float_as_int(v), 0x101F))
#define SH_X8(v)  __int_as_float(__builtin_amdgcn_ds_swizzle(__float_as_int(v), 0x201F))
#define SH_X16(v) __int_as_float(__builtin_amdgcn_ds_swizzle(__float_as_int(v), 0x401F))
#define SH_X32(v) __shfl_xor((v), 32, 64)

// One shuffle-butterfly stage: fetch all 8 partner values, then 8 one-sided
// rotations. 8-wide ILP, no barrier, no LDS storage.
#define SHSTAGE(SH, c0,c1,c2,c3,c4,c5,c6,c7) do {                          \
    float p0_ = SH(z0); float p1_ = SH(z1);                                \
    float p2_ = SH(z2); float p3_ = SH(z3);                                \
    float p4_ = SH(z4); float p5_ = SH(z5);                                \
    float p6_ = SH(z6); float p7_ = SH(z7);                                \
    ROT1(z0, p0_, c0); ROT1(z1, p1_, c1);                                  \
    ROT1(z2, p2_, c2); ROT1(z3, p3_, c3);                                  \
    ROT1(z4, p4_, c4); ROT1(z5, p5_, c5);                                  \
    ROT1(z6, p6_, c6); ROT1(z7, p7_, c7);                                  \
  } while (0)

__global__ __launch_bounds__(BLOCK, 2) void butterfly12_kernel(
    const float* __restrict__ xin,
    const float* __restrict__ ang,   // [12][2048] fp32
    float* __restrict__ xout) {
  __shared__ float lds[2 * NCOL];    // two ping-pong exchange images, 32 KB

  const int t = threadIdx.x;

  // ---------- per-thread packed (cos-1, sgn*sin) preload ----------
  // Group A (stages 0-2, in-thread): contiguous angles 4t..4t+3 per stage.
  const floatx4 aA0 = *(const floatx4*)(ang + 0 * 2048 + 4 * t);
  const floatx4 aA1 = *(const floatx4*)(ang + 1 * 2048 + 4 * t);
  const floatx4 aA2 = *(const floatx4*)(ang + 2 * 2048 + 4 * t);
  const unsigned int k0  = pack_cs(aA0.x, 1.f), k1  = pack_cs(aA0.y, 1.f),
                     k2  = pack_cs(aA0.z, 1.f), k3  = pack_cs(aA0.w, 1.f);
  const unsigned int k4  = pack_cs(aA1.x, 1.f), k5  = pack_cs(aA1.y, 1.f),
                     k6  = pack_cs(aA1.z, 1.f), k7  = pack_cs(aA1.w, 1.f);
  const unsigned int k8  = pack_cs(aA2.x, 1.f), k9  = pack_cs(aA2.y, 1.f),
                     k10 = pack_cs(aA2.z, 1.f), k11 = pack_cs(aA2.w, 1.f);

  // Shuffle stages 3-8: 8 contiguous angles per stage; sigma by (t & Delta).
  const float* q3 = ang + 3 * 2048 +   8 * (t >> 1);
  const float* q4 = ang + 4 * 2048 +  16 * (t >> 2) + 8 * (t & 1);
  const float* q5 = ang + 5 * 2048 +  32 * (t >> 3) + 8 * (t & 3);
  const float* q6 = ang + 6 * 2048 +  64 * (t >> 4) + 8 * (t & 7);
  const float* q7 = ang + 7 * 2048 + 128 * (t >> 5) + 8 * (t & 15);
  const float* q8 = ang + 8 * 2048 + 256 * (t >> 6) + 8 * (t & 31);
  const float g3 = (t & 1)  ? 1.f : -1.f;
  const float g4 = (t & 2)  ? 1.f : -1.f;
  const float g5 = (t & 4)  ? 1.f : -1.f;
  const float g6 = (t & 8)  ? 1.f : -1.f;
  const float g7 = (t & 16) ? 1.f : -1.f;
  const float g8 = (t & 32) ? 1.f : -1.f;
  const floatx4 a3l = *(const floatx4*)q3, a3h = *(const floatx4*)(q3 + 4);
  const floatx4 a4l = *(const floatx4*)q4, a4h = *(const floatx4*)(q4 + 4);
  const floatx4 a5l = *(const floatx4*)q5, a5h = *(const floatx4*)(q5 + 4);
  const floatx4 a6l = *(const floatx4*)q6, a6h = *(const floatx4*)(q6 + 4);
  const floatx4 a7l = *(const floatx4*)q7, a7h = *(const floatx4*)(q7 + 4);
  const floatx4 a8l = *(const floatx4*)q8, a8h = *(const floatx4*)(q8 + 4);
  const unsigned int s30 = pack_cs(a3l.x, g3), s31 = pack_cs(a3l.y, g3),
                     s32 = pack_cs(a3l.z, g3), s33 = pack_cs(a3l.w, g3),
                     s34 = pack_cs(a3h.x, g3), s35 = pack_cs(a3h.y, g3),
                     s36 = pack_cs(a3h.z, g3), s37 = pack_cs(a3h.w, g3);
  const unsigned int s40 = pack_cs(a4l.x, g4), s41 = pack_cs(a4l.y, g4),
                     s42 = pack_cs(a4l.z, g4), s43 = pack_cs(a4l.w, g4),
                     s44 = pack_cs(a4h.x, g4), s45 = pack_cs(a4h.y, g4),
                     s46 = pack_cs(a4h.z, g4), s47 = pack_cs(a4h.w, g4);
  const unsigned int s50 = pack_cs(a5l.x, g5), s51 = pack_cs(a5l.y, g5),
                     s52 = pack_cs(a5l.z, g5), s53 = pack_cs(a5l.w, g5),
                     s54 = pack_cs(a5h.x, g5), s55 = pack_cs(a5h.y, g5),
                     s56 = pack_cs(a5h.z, g5), s57 = pack_cs(a5h.w, g5);
  const unsigned int s60 = pack_cs(a6l.x, g6), s61 = pack_cs(a6l.y, g6),
                     s62 = pack_cs(a6l.z, g6), s63 = pack_cs(a6l.w, g6),
                     s64 = pack_cs(a6h.x, g6), s65 = pack_cs(a6h.y, g6),
                     s66 = pack_cs(a6h.z, g6), s67 = pack_cs(a6h.w, g6);
  const unsigned int s70 = pack_cs(a7l.x, g7), s71 = pack_cs(a7l.y, g7),
                     s72 = pack_cs(a7l.z, g7), s73 = pack_cs(a7l.w, g7),
                     s74 = pack_cs(a7h.x, g7), s75 = pack_cs(a7h.y, g7),
                     s76 = pack_cs(a7h.z, g7), s77 = pack_cs(a7h.w, g7);
  const unsigned int s80 = pack_cs(a8l.x, g8), s81 = pack_cs(a8l.y, g8),
                     s82 = pack_cs(a8l.z, g8), s83 = pack_cs(a8l.w, g8),
                     s84 = pack_cs(a8h.x, g8), s85 = pack_cs(a8h.y, g8),
                     s86 = pack_cs(a8h.z, g8), s87 = pack_cs(a8h.w, g8);

  // Group D (stages 9-11, in-thread after exchange): base t, stride 512.
  const float* pD0 = ang + 9 * 2048 + t;
  const float* pD1 = pD0 + 2048;
  const float* pD2 = pD1 + 2048;
  const unsigned int d0 = pack_cs(pD0[0], 1.f),    d1 = pack_cs(pD0[512], 1.f),
                     d2 = pack_cs(pD0[1024], 1.f), d3 = pack_cs(pD0[1536], 1.f);
  const unsigned int d4 = pack_cs(pD1[0], 1.f),    d5 = pack_cs(pD1[512], 1.f),
                     d6 = pack_cs(pD1[1024], 1.f), d7 = pack_cs(pD1[1536], 1.f);
  const unsigned int d8 = pack_cs(pD2[0], 1.f),    d9 = pack_cs(pD2[512], 1.f),
                     d10 = pack_cs(pD2[1024], 1.f), d11 = pack_cs(pD2[1536], 1.f);

  // ---------- row loop ----------
  const long long row0 = (long long)blockIdx.x * NROWS;
  const float* xbase = xin + row0 * NCOL + 8 * t;
  floatx4 rawA = __builtin_nontemporal_load((const floatx4*)xbase);
  floatx4 rawB = __builtin_nontemporal_load((const floatx4*)(xbase + 4));

  for (int rI = 0; rI < NROWS; ++rI) {
    float z0 = rawA.x, z1 = rawA.y, z2 = rawA.z, z3 = rawA.w;
    float z4 = rawB.x, z5 = rawB.y, z6 = rawB.z, z7 = rawB.w;
    if (rI + 1 < NROWS) {                       // prefetch next row (nt)
      const float* nbase = xbase + (long long)(rI + 1) * NCOL;
      rawA = __builtin_nontemporal_load((const floatx4*)nbase);
      rawB = __builtin_nontemporal_load((const floatx4*)(nbase + 4));
    }

    GROUP3(k0, k1, k2, k3, k4, k5, k6, k7, k8, k9, k10, k11);  // stages 0-2

    SHSTAGE(SH_X1,  s30, s31, s32, s33, s34, s35, s36, s37);   // stage 3
    SHSTAGE(SH_X2,  s40, s41, s42, s43, s44, s45, s46, s47);   // stage 4
    SHSTAGE(SH_X4,  s50, s51, s52, s53, s54, s55, s56, s57);   // stage 5
    SHSTAGE(SH_X8,  s60, s61, s62, s63, s64, s65, s66, s67);   // stage 6
    SHSTAGE(SH_X16, s70, s71, s72, s73, s74, s75, s76, s77);   // stage 7
    SHSTAGE(SH_X32, s80, s81, s82, s83, s84, s85, s86, s87);   // stage 8

    // Single cross-wave exchange: natural layout, ping-pong image.
    float* im = lds + ((rI & 1) << 12);
    floatx4 w0; w0.x = z0; w0.y = z1; w0.z = z2; w0.w = z3;
    floatx4 w1; w1.x = z4; w1.y = z5; w1.z = z6; w1.w = z7;
    *(floatx4*)(im + 8 * t) = w0;               // 2x ds_write_b128
    *(floatx4*)(im + 8 * t + 4) = w1;
    __syncthreads();                            // the ONLY barrier this row

    z0 = im[t + 512 * 0]; z1 = im[t + 512 * 1]; // stride-512: lane-stride-1,
    z2 = im[t + 512 * 2]; z3 = im[t + 512 * 3]; // conflict-free
    z4 = im[t + 512 * 4]; z5 = im[t + 512 * 5];
    z6 = im[t + 512 * 6]; z7 = im[t + 512 * 7];

    GROUP3(d0, d1, d2, d3, d4, d5, d6, d7, d8, d9, d10, d11);  // stages 9-11

    float* orow = xout + (row0 + rI) * NCOL;    // coalesced out
    __builtin_nontemporal_store(z0, orow + t + 512 * 0);
    __builtin_nontemporal_store(z1, orow + t + 512 * 1);
    __builtin_nontemporal_store(z2, orow + t + 512 * 2);
    __builtin_nontemporal_store(z3, orow + t + 512 * 3);
    __builtin_nontemporal_store(z4, orow + t + 512 * 4);
    __builtin_nontemporal_store(z5, orow + t + 512 * 5);
    __builtin_nontemporal_store(z6, orow + t + 512 * 6);
    __builtin_nontemporal_store(z7, orow + t + 512 * 7);
    // No trailing barrier: row r+2's writes to this image are ordered after
    // barrier_{r+1}, which follows every thread's row-r reads (program order:
    // read_r -> write_{r+1} -> barrier_{r+1}).
  }
}

extern "C" void kernel_launch(void* const* d_in, const int* in_sizes, int n_in,
                              void* d_out, int out_size, void* d_ws, size_t ws_size,
                              hipStream_t stream) {
  const float* x   = (const float*)d_in[0];   // fp32 [4096][4096]
  const float* ang = (const float*)d_in[1];   // fp32 [12][2048]
  float* out = (float*)d_out;                 // fp32 [4096][4096]
  butterfly12_kernel<<<dim3(4096 / NROWS), dim3(BLOCK), 0, stream>>>(x, ang, out);
}

// Round 2
// 127.950 us; speedup vs baseline: 1.0057x; 1.0057x over previous
//
#include <hip/hip_runtime.h>

// StabilizedButterflyLayer: B=4096 rows, N=4096 cols, 12 butterfly stages.
// fp32 in / fp32 out.
//
// R6: prefetch depth 2 (two named register buffers, row loop unrolled x2,
// all indices static). R5's null result (deleting 2/3 of the LDS exchanges
// changed nothing) proved LDS/barrier work is NOT on the critical path; the
// kernel is memory-dominated. With 2 blocks/CU and prefetch-1, a row's NT
// load had only ~1 row of compute (~700 cy) to cover ~900 cy HBM latency.
// Depth-2 gives ~2 rows of cover. If this is ALSO null, the kernel is at
// its HBM floor and the measured total is harness-fill-dominated.
//
// Structure (from R5, kept): stages 0-2 in-thread (contig-8 layout);
// stages 3-8 as in-wave shuffle butterflies (DPP quad_perm ^1/^2,
// ds_swizzle ^4/^8/^16, shfl_xor ^32) -- no barrier, no LDS; stages 9-11
// in-thread after ONE LDS exchange (natural write, stride-512 read,
// ping-pong over 2 images, 1 barrier/row). Comms-minimal: bits 9-11 of the
// element index are wave-index bits -> cross-wave exchange is unavoidable.
//
// One-sided rotation for shuffle stages: z' = c*z + sigma*s*p, sigma baked
// into the packed bf16 sin (bit-identical to two-sided; absmax 0.03125 =
// harness's own bf16 reference quantization floor).
//
// 2-image / 1-barrier WAR safety (unchanged by prefetch): row r uses image
// r&1; thread Y's write of row r+2 (image p) is after barrier_{r+1}; every
// thread's read of row r (image p) precedes its own barrier_{r+1}.
//
// R4 lesson: __launch_bounds__(512, 2) -> 128-VGPR cap, 2 blocks/CU.
// Est. live set now: 72 packed angles + 16 prefetch + 8 z + addrs ~= 120.
// R3 lesson: nontemporal builtins need clang ext_vector_type, not float4.
// R2 lesson: keep everything scalarized, no address-taken locals,
//            no runtime-indexed register arrays (-> scratch).

#define BLOCK 512
#define NROWS 8
#define NCOL  4096

typedef float floatx4 __attribute__((ext_vector_type(4)));

// theta -> packed {hi16: bf16(sgn*sin), lo16: bf16(cos-1)}; |theta| <~ 0.17
// so the 2-term polys are exact to ~1e-5.
__device__ __forceinline__ unsigned int pack_cs(float th, float sgn) {
  float t2  = th * th;
  float s   = sgn * (th * fmaf(t2, fmaf(t2, 8.3333333e-3f, -1.6666667e-1f), 1.0f));
  float cm1 = t2 * fmaf(t2, 4.1666667e-2f, -0.5f);
  unsigned int uc = __float_as_uint(cm1);
  uc = (uc + 0x7fffu + ((uc >> 16) & 1u)) >> 16;
  unsigned int us = __float_as_uint(s);
  us = (us + 0x7fffu + ((us >> 16) & 1u)) & 0xffff0000u;
  return us | uc;
}

// Two-sided Givens on an owned pair: a' = c*a - s*b ; b' = s*a + c*b
#define ROT(a, b, cc) do {                                   \
    float cm1_ = __uint_as_float((cc) << 16);                \
    float s_   = __uint_as_float((cc) & 0xffff0000u);        \
    float y0_  = fmaf(cm1_, (a), fmaf(-s_, (b), (a)));       \
    float y1_  = fmaf(cm1_, (b), fmaf( s_, (a), (b)));       \
    (a) = y0_; (b) = y1_;                                    \
  } while (0)

// One-sided: z' = c*z + s_signed*p  (sigma pre-baked into packed sin)
#define ROT1(z, p, cc) do {                                  \
    float cm1_ = __uint_as_float((cc) << 16);                \
    float ss_  = __uint_as_float((cc) & 0xffff0000u);        \
    (z) = fmaf(cm1_, (z), fmaf(ss_, (p), (z)));              \
  } while (0)

// 3 in-thread stages (slot maps verified in R2).
#define GROUP3(c0,c1,c2,c3,c4,c5,c6,c7,c8,c9,c10,c11) do {   \
    ROT(z0, z1, c0);  ROT(z2, z3, c1);                       \
    ROT(z4, z5, c2);  ROT(z6, z7, c3);                       \
    ROT(z0, z2, c4);  ROT(z1, z3, c5);                       \
    ROT(z4, z6, c6);  ROT(z5, z7, c7);                       \
    ROT(z0, z4, c8);  ROT(z1, z5, c9);                       \
    ROT(z2, z6, c10); ROT(z3, z7, c11);                      \
  } while (0)

// Cross-lane fetch of partner value, by thread-XOR distance.
#define SH_X1(v)  __int_as_float(__builtin_amdgcn_update_dpp(              \
    __float_as_int(v), __float_as_int(v), 0xB1, 0xF, 0xF, false))
#define SH_X2(v)  __int_as_float(__builtin_amdgcn_update_dpp(              \
    __float_as_int(v), __float_as_int(v), 0x4E, 0xF, 0xF, false))
#define SH_X4(v)  __int_as_float(__builtin_amdgcn_ds_swizzle(__float_as_int(v), 0x101F))
#define SH_X8(v)  __int_as_float(__builtin_amdgcn_ds_swizzle(__float_as_int(v), 0x201F))
#define SH_X16(v) __int_as_float(__builtin_amdgcn_ds_swizzle(__float_as_int(v), 0x401F))
#define SH_X32(v) __shfl_xor((v), 32, 64)

#define SHSTAGE(SH, c0,c1,c2,c3,c4,c5,c6,c7) do {                          \
    float p0_ = SH(z0); float p1_ = SH(z1);                                \
    float p2_ = SH(z2); float p3_ = SH(z3);                                \
    float p4_ = SH(z4); float p5_ = SH(z5);                                \
    float p6_ = SH(z6); float p7_ = SH(z7);                                \
    ROT1(z0, p0_, c0); ROT1(z1, p1_, c1);                                  \
    ROT1(z2, p2_, c2); ROT1(z3, p3_, c3);                                  \
    ROT1(z4, p4_, c4); ROT1(z5, p5_, c5);                                  \
    ROT1(z6, p6_, c6); ROT1(z7, p7_, c7);                                  \
  } while (0)

#define NTLD(p) __builtin_nontemporal_load((const floatx4*)(p))

__global__ __launch_bounds__(BLOCK, 2) void butterfly12_kernel(
    const float* __restrict__ xin,
    const float* __restrict__ ang,   // [12][2048] fp32
    float* __restrict__ xout) {
  __shared__ float lds[2 * NCOL];    // two ping-pong exchange images, 32 KB

  const int t = threadIdx.x;

  // ---------- per-thread packed (cos-1, sgn*sin) preload ----------
  // Group A (stages 0-2, in-thread): contiguous angles 4t..4t+3 per stage.
  const floatx4 aA0 = *(const floatx4*)(ang + 0 * 2048 + 4 * t);
  const floatx4 aA1 = *(const floatx4*)(ang + 1 * 2048 + 4 * t);
  const floatx4 aA2 = *(const floatx4*)(ang + 2 * 2048 + 4 * t);
  const unsigned int k0  = pack_cs(aA0.x, 1.f), k1  = pack_cs(aA0.y, 1.f),
                     k2  = pack_cs(aA0.z, 1.f), k3  = pack_cs(aA0.w, 1.f);
  const unsigned int k4  = pack_cs(aA1.x, 1.f), k5  = pack_cs(aA1.y, 1.f),
                     k6  = pack_cs(aA1.z, 1.f), k7  = pack_cs(aA1.w, 1.f);
  const unsigned int k8  = pack_cs(aA2.x, 1.f), k9  = pack_cs(aA2.y, 1.f),
                     k10 = pack_cs(aA2.z, 1.f), k11 = pack_cs(aA2.w, 1.f);

  // Shuffle stages 3-8: 8 contiguous angles per stage; sigma by (t & Delta).
  const float* q3 = ang + 3 * 2048 +   8 * (t >> 1);
  const float* q4 = ang + 4 * 2048 +  16 * (t >> 2) + 8 * (t & 1);
  const float* q5 = ang + 5 * 2048 +  32 * (t >> 3) + 8 * (t & 3);
  const float* q6 = ang + 6 * 2048 +  64 * (t >> 4) + 8 * (t & 7);
  const float* q7 = ang + 7 * 2048 + 128 * (t >> 5) + 8 * (t & 15);
  const float* q8 = ang + 8 * 2048 + 256 * (t >> 6) + 8 * (t & 31);
  const float g3 = (t & 1)  ? 1.f : -1.f;
  const float g4 = (t & 2)  ? 1.f : -1.f;
  const float g5 = (t & 4)  ? 1.f : -1.f;
  const float g6 = (t & 8)  ? 1.f : -1.f;
  const float g7 = (t & 16) ? 1.f : -1.f;
  const float g8 = (t & 32) ? 1.f : -1.f;
  const floatx4 a3l = *(const floatx4*)q3, a3h = *(const floatx4*)(q3 + 4);
  const floatx4 a4l = *(const floatx4*)q4, a4h = *(const floatx4*)(q4 + 4);
  const floatx4 a5l = *(const floatx4*)q5, a5h = *(const floatx4*)(q5 + 4);
  const floatx4 a6l = *(const floatx4*)q6, a6h = *(const floatx4*)(q6 + 4);
  const floatx4 a7l = *(const floatx4*)q7, a7h = *(const floatx4*)(q7 + 4);
  const floatx4 a8l = *(const floatx4*)q8, a8h = *(const floatx4*)(q8 + 4);
  const unsigned int s30 = pack_cs(a3l.x, g3), s31 = pack_cs(a3l.y, g3),
                     s32 = pack_cs(a3l.z, g3), s33 = pack_cs(a3l.w, g3),
                     s34 = pack_cs(a3h.x, g3), s35 = pack_cs(a3h.y, g3),
                     s36 = pack_cs(a3h.z, g3), s37 = pack_cs(a3h.w, g3);
  const unsigned int s40 = pack_cs(a4l.x, g4), s41 = pack_cs(a4l.y, g4),
                     s42 = pack_cs(a4l.z, g4), s43 = pack_cs(a4l.w, g4),
                     s44 = pack_cs(a4h.x, g4), s45 = pack_cs(a4h.y, g4),
                     s46 = pack_cs(a4h.z, g4), s47 = pack_cs(a4h.w, g4);
  const unsigned int s50 = pack_cs(a5l.x, g5), s51 = pack_cs(a5l.y, g5),
                     s52 = pack_cs(a5l.z, g5), s53 = pack_cs(a5l.w, g5),
                     s54 = pack_cs(a5h.x, g5), s55 = pack_cs(a5h.y, g5),
                     s56 = pack_cs(a5h.z, g5), s57 = pack_cs(a5h.w, g5);
  const unsigned int s60 = pack_cs(a6l.x, g6), s61 = pack_cs(a6l.y, g6),
                     s62 = pack_cs(a6l.z, g6), s63 = pack_cs(a6l.w, g6),
                     s64 = pack_cs(a6h.x, g6), s65 = pack_cs(a6h.y, g6),
                     s66 = pack_cs(a6h.z, g6), s67 = pack_cs(a6h.w, g6);
  const unsigned int s70 = pack_cs(a7l.x, g7), s71 = pack_cs(a7l.y, g7),
                     s72 = pack_cs(a7l.z, g7), s73 = pack_cs(a7l.w, g7),
                     s74 = pack_cs(a7h.x, g7), s75 = pack_cs(a7h.y, g7),
                     s76 = pack_cs(a7h.z, g7), s77 = pack_cs(a7h.w, g7);
  const unsigned int s80 = pack_cs(a8l.x, g8), s81 = pack_cs(a8l.y, g8),
                     s82 = pack_cs(a8l.z, g8), s83 = pack_cs(a8l.w, g8),
                     s84 = pack_cs(a8h.x, g8), s85 = pack_cs(a8h.y, g8),
                     s86 = pack_cs(a8h.z, g8), s87 = pack_cs(a8h.w, g8);

  // Group D (stages 9-11, in-thread after exchange): base t, stride 512.
  const float* pD0 = ang + 9 * 2048 + t;
  const float* pD1 = pD0 + 2048;
  const float* pD2 = pD1 + 2048;
  const unsigned int d0 = pack_cs(pD0[0], 1.f),    d1 = pack_cs(pD0[512], 1.f),
                     d2 = pack_cs(pD0[1024], 1.f), d3 = pack_cs(pD0[1536], 1.f);
  const unsigned int d4 = pack_cs(pD1[0], 1.f),    d5 = pack_cs(pD1[512], 1.f),
                     d6 = pack_cs(pD1[1024], 1.f), d7 = pack_cs(pD1[1536], 1.f);
  const unsigned int d8 = pack_cs(pD2[0], 1.f),    d9 = pack_cs(pD2[512], 1.f),
                     d10 = pack_cs(pD2[1024], 1.f), d11 = pack_cs(pD2[1536], 1.f);

  // ---------- row loop: prefetch depth 2, unrolled x2, static buffers ----
  const long long row0 = (long long)blockIdx.x * NROWS;
  const float* xb = xin + row0 * NCOL + 8 * t;

  // Full 12-stage body for one row; consumes z0..z7, writes output row.
  // IMAGE: this row's ping-pong LDS image base. OROW: output row pointer.
#define ROWBODY(IMAGE, OROW) do {                                          \
    GROUP3(k0, k1, k2, k3, k4, k5, k6, k7, k8, k9, k10, k11);              \
    SHSTAGE(SH_X1,  s30, s31, s32, s33, s34, s35, s36, s37);               \
    SHSTAGE(SH_X2,  s40, s41, s42, s43, s44, s45, s46, s47);               \
    SHSTAGE(SH_X4,  s50, s51, s52, s53, s54, s55, s56, s57);               \
    SHSTAGE(SH_X8,  s60, s61, s62, s63, s64, s65, s66, s67);               \
    SHSTAGE(SH_X16, s70, s71, s72, s73, s74, s75, s76, s77);               \
    SHSTAGE(SH_X32, s80, s81, s82, s83, s84, s85, s86, s87);               \
    floatx4 w0; w0.x = z0; w0.y = z1; w0.z = z2; w0.w = z3;                \
    floatx4 w1; w1.x = z4; w1.y = z5; w1.z = z6; w1.w = z7;                \
    *(floatx4*)((IMAGE) + 8 * t) = w0;                                     \
    *(floatx4*)((IMAGE) + 8 * t + 4) = w1;                                 \
    __syncthreads();                                                       \
    z0 = (IMAGE)[t + 512 * 0]; z1 = (IMAGE)[t + 512 * 1];                  \
    z2 = (IMAGE)[t + 512 * 2]; z3 = (IMAGE)[t + 512 * 3];                  \
    z4 = (IMAGE)[t + 512 * 4]; z5 = (IMAGE)[t + 512 * 5];                  \
    z6 = (IMAGE)[t + 512 * 6]; z7 = (IMAGE)[t + 512 * 7];                  \
    GROUP3(d0, d1, d2, d3, d4, d5, d6, d7, d8, d9, d10, d11);              \
    __builtin_nontemporal_store(z0, (OROW) + t + 512 * 0);                 \
    __builtin_nontemporal_store(z1, (OROW) + t + 512 * 1);                 \
    __builtin_nontemporal_store(z2, (OROW) + t + 512 * 2);                 \
    __builtin_nontemporal_store(z3, (OROW) + t + 512 * 3);                 \
    __builtin_nontemporal_store(z4, (OROW) + t + 512 * 4);                 \
    __builtin_nontemporal_store(z5, (OROW) + t + 512 * 5);                 \
    __builtin_nontemporal_store(z6, (OROW) + t + 512 * 6);                 \
    __builtin_nontemporal_store(z7, (OROW) + t + 512 * 7);                 \
  } while (0)

  // Prime: rows 0 and 1 in flight.
  floatx4 b0A = NTLD(xb + 0 * NCOL), b0B = NTLD(xb + 0 * NCOL + 4);
  floatx4 b1A = NTLD(xb + 1 * NCOL), b1B = NTLD(xb + 1 * NCOL + 4);

  for (int r = 0; r < NROWS; r += 2) {
    {   // even row r: consume b0, refill b0 with row r+2 (2 rows ahead)
      float z0 = b0A.x, z1 = b0A.y, z2 = b0A.z, z3 = b0A.w;
      float z4 = b0B.x, z5 = b0B.y, z6 = b0B.z, z7 = b0B.w;
      if (r < NROWS - 2) {
        const float* nb = xb + (long long)(r + 2) * NCOL;
        b0A = NTLD(nb); b0B = NTLD(nb + 4);
      }
      ROWBODY(lds, xout + (row0 + r) * NCOL);
    }
    {   // odd row r+1: consume b1, refill b1 with row r+3
      float z0 = b1A.x, z1 = b1A.y, z2 = b1A.z, z3 = b1A.w;
      float z4 = b1B.x, z5 = b1B.y, z6 = b1B.z, z7 = b1B.w;
      if (r < NROWS - 3) {
        const float* nb = xb + (long long)(r + 3) * NCOL;
        b1A = NTLD(nb); b1B = NTLD(nb + 4);
      }
      ROWBODY(lds + 4096, xout + (row0 + r + 1) * NCOL);
    }
  }
#undef ROWBODY
}

extern "C" void kernel_launch(void* const* d_in, const int* in_sizes, int n_in,
                              void* d_out, int out_size, void* d_ws, size_t ws_size,
                              hipStream_t stream) {
  const float* x   = (const float*)d_in[0];   // fp32 [4096][4096]
  const float* ang = (const float*)d_in[1];   // fp32 [12][2048]
  float* out = (float*)d_out;                 // fp32 [4096][4096]
  butterfly12_kernel<<<dim3(4096 / NROWS), dim3(BLOCK), 0, stream>>>(x, ang, out);
}